// Round 14
// baseline (399.091 us; speedup 1.0000x reference)
//
#include <hip/hip_runtime.h>
#include <hip/hip_bf16.h>
#include <math.h>

#define KDIM 5
#define KC 125
#define KPAD 8192   // 125*64 spline rows + 64 root rows + 128 zero pad (levels 2/3)
#define EPB 32      // max_nb = 32 -> deg <= 32 always
#define NSPLIT 8    // GEMM K-split for levels 2/3 (1024 blocks -> 4/CU TLP)
#define SSTR 40     // buildA S row stride in bf16
#define XSTR 40     // buildA XT row stride in bf16
#define H1STR 40    // histo1 S row stride in bf16
#define MAXCHUNK 8192  // cap Abuf chunk at 128 MB so buildA->gemm stays L3-resident

typedef short bf16x8 __attribute__((ext_vector_type(8)));
typedef float f32x4 __attribute__((ext_vector_type(4)));

__device__ __forceinline__ float elu_f(float x) { return x > 0.f ? x : (expf(x) - 1.f); }

__device__ __forceinline__ void fadd_atomic(float* p, float v) {
    unsafeAtomicAdd(p, v);
}

__device__ __forceinline__ unsigned short f2bf(float x) {
    union { float f; unsigned u; } v; v.f = x;
    unsigned r = (v.u + 0x7FFFu + ((v.u >> 16) & 1u)) >> 16;
    return (unsigned short)r;
}

// async 16B global->LDS (dest = wave-uniform base + lane*16)
__device__ __forceinline__ void gll16(const unsigned short* g, unsigned short* l) {
    __builtin_amdgcn_global_load_lds(
        (const __attribute__((address_space(1))) unsigned int*)g,
        (__attribute__((address_space(3))) unsigned int*)l, 16, 0, 0);
}

// inline spline-weight scatter (w==0 duplicates -> sinkrow)
__device__ __forceinline__ void spline_scatter(
    const float* __restrict__ posL, int s, int node, float rinv2, int sinkrow,
    unsigned short* __restrict__ S, int stride, int ecol)
{
    float p0 = fminf(fmaxf((posL[node*3+0] - posL[s*3+0]) * rinv2 + 0.5f, 0.f), 1.f);
    float p1 = fminf(fmaxf((posL[node*3+1] - posL[s*3+1]) * rinv2 + 0.5f, 0.f), 1.f);
    float p2 = fminf(fmaxf((posL[node*3+2] - posL[s*3+2]) * rinv2 + 0.5f, 0.f), 1.f);
    float v0 = p0 * (KDIM - 1), v1 = p1 * (KDIM - 1), v2 = p2 * (KDIM - 1);
    int b0 = (int)floorf(v0), b1 = (int)floorf(v1), b2 = (int)floorf(v2);
    float f0 = v0 - (float)b0, f1 = v1 - (float)b1, f2 = v2 - (float)b2;
    #pragma unroll
    for (int sb = 0; sb < 8; sb++) {
        int i0 = sb & 1, i1 = (sb >> 1) & 1, i2 = (sb >> 2) & 1;
        float w = (i0 ? f0 : 1.f - f0) * (i1 ? f1 : 1.f - f1) * (i2 ? f2 : 1.f - f2);
        int k0 = min(b0 + i0, KDIM - 1), k1 = min(b1 + i1, KDIM - 1), k2 = min(b2 + i2, KDIM - 1);
        int wi = k0 + KDIM * k1 + KDIM * KDIM * k2;
        if (w == 0.f) wi = sinkrow;
        S[wi * stride + ecol] = f2bf(w);
    }
}

// ---------------- rowptr segment ----------------
__device__ __forceinline__ void rowptr_seg(const int* __restrict__ tgt, int E, int n,
                                           int* __restrict__ rowptr, int e)
{
    if (e < E) {
        int t = tgt[e];
        int p = (e == 0) ? -1 : tgt[e - 1];
        for (int v = p + 1; v <= t; v++) rowptr[v] = e;
    } else {   // e == E
        int p = tgt[E - 1];
        for (int v = p + 1; v <= n; v++) rowptr[v] = E;
    }
}

// pre: pos gathers + rowptr x3 + cid/cnt -- single launch.
// gnum/cnt zeroed by stream-ordered hipMemsetAsync BEFORE this launch (round-12 lesson).
__global__ void pre_kernel(
    const float* __restrict__ pos, const int* __restrict__ idx1, const int* __restrict__ idx2,
    int n2, int n3,
    float* __restrict__ pos2, float* __restrict__ pos3,
    const int* __restrict__ tgt1, int E1, int n1, int* __restrict__ rp1,
    const int* __restrict__ tgt2, int E2, int* __restrict__ rp2,
    const int* __restrict__ tgt3, int E3, int* __restrict__ rp3,
    const int* __restrict__ batch, int* __restrict__ cid, float* __restrict__ cnt)
{
    int i = blockIdx.x * blockDim.x + threadIdx.x;
    int w0 = n2 * 3, w1 = w0 + n3 * 3;
    int e0 = w1 + E1 + 1, e1 = e0 + E2 + 1, e2 = e1 + E3 + 1, e3 = e2 + n3;
    if (i < w0) {
        int r = i / 3, d = i - r * 3;
        pos2[i] = pos[idx1[r] * 3 + d];
    } else if (i < w1) {
        int j = i - w0;
        int r = j / 3, d = j - r * 3;
        pos3[j] = pos[idx1[idx2[r]] * 3 + d];
    } else if (i < e0) {
        rowptr_seg(tgt1, E1, n1, rp1, i - w1);
    } else if (i < e1) {
        rowptr_seg(tgt2, E2, n2, rp2, i - e0);
    } else if (i < e2) {
        rowptr_seg(tgt3, E3, n3, rp3, i - e1);
    } else if (i < e3) {
        int j = i - e2;
        int cl = batch[idx1[idx2[j]]];
        cid[j] = cl;
        int lane = threadIdx.x & 63;
        #pragma unroll
        for (int c = 0; c < 16; c++) {
            unsigned long long m = __ballot(cl == c);
            if (m != 0ULL && lane == __ffsll((long long)m) - 1)
                fadd_atomic(&cnt[c], (float)__popcll(m));
        }
    }
}

// ---------------- tiled transpose, all three weight sets in ONE launch ------------
__global__ __launch_bounds__(256) void wtT_kernel(
    const float* __restrict__ W1, const float* __restrict__ R1, unsigned short* __restrict__ WfT1,
    const float* __restrict__ W2, const float* __restrict__ R2, unsigned short* __restrict__ WfT2,
    const float* __restrict__ W3, const float* __restrict__ R3, unsigned short* __restrict__ WfT3)
{
    __shared__ unsigned short L[64 * 65];
    int bt = blockIdx.x;
    const float *W, *R;
    unsigned short* WfT;
    int COUT, kpad, krows, cin, ntk;
    if (bt < 2)        { W = W1; R = R1; WfT = WfT1; COUT = 64;  kpad = 128;  krows = KC;      cin = 1;  ntk = 2;   }
    else if (bt < 130) { W = W2; R = R2; WfT = WfT2; COUT = 64;  kpad = KPAD; krows = KC * 64; cin = 64; ntk = 128; bt -= 2;   }
    else               { W = W3; R = R3; WfT = WfT3; COUT = 128; kpad = KPAD; krows = KC * 64; cin = 64; ntk = 128; bt -= 130; }
    int kt = (bt % ntk) * 64;
    int nt = (bt / ntk) * 64;
    int t = threadIdx.x;
    int ncol = t & 63, rowgrp = t >> 6;
    #pragma unroll
    for (int j = 0; j < 16; j++) {
        int row = j * 4 + rowgrp;     // 0..63
        int k = kt + row;
        int n = nt + ncol;
        float v = 0.f;
        if (k < krows) v = W[(size_t)k * COUT + n];
        else if (k < krows + cin) v = R[(size_t)(k - krows) * COUT + n];
        L[row * 65 + ncol] = f2bf(v);
    }
    __syncthreads();
    int n = nt + (t >> 2);
    int k0 = (t & 3) * 16;
    __attribute__((aligned(16))) unsigned short tmp[16];
    #pragma unroll
    for (int j = 0; j < 16; j++) tmp[j] = L[(k0 + j) * 65 + (t >> 2)];
    *(uint4*)&WfT[(size_t)n * kpad + kt + k0]     = *(uint4*)&tmp[0];
    *(uint4*)&WfT[(size_t)n * kpad + kt + k0 + 8] = *(uint4*)&tmp[8];
}

// ---------------- Level 1 histogram via MFMA row-sum, inline slot computation ------
__global__ __launch_bounds__(256) void histo1_kernel(const float* __restrict__ pos,
                                                     const int* __restrict__ src,
                                                     const int* __restrict__ rowptr,
                                                     float rinv2, int sinkrow,
                                                     unsigned short* __restrict__ Aout)
{
    __shared__ __attribute__((aligned(16))) unsigned short S[4][128 * H1STR];
    int wave = threadIdx.x >> 6, lane = threadIdx.x & 63;
    int node = blockIdx.x * 4 + wave;
    int rs = rowptr[node], re = rowptr[node + 1];
    int deg = re - rs;
    unsigned short* Sw = S[wave];

    for (int i = lane; i < 128 * H1STR / 8; i += 64)
        ((uint4*)Sw)[i] = make_uint4(0, 0, 0, 0);
    __syncthreads();

    if (lane < deg)
        spline_scatter(pos, src[rs + lane], node, rinv2, sinkrow, Sw, H1STR, lane);
    __syncthreads();

    const short one = 0x3F80;
    bf16x8 bones = {one, one, one, one, one, one, one, one};
    int fr = lane & 15, fq = (lane >> 4) * 8;
    f32x4 acc[8];
    #pragma unroll
    for (int tl = 0; tl < 8; tl++) {
        bf16x8 af = *(const bf16x8*)&Sw[(tl * 16 + fr) * H1STR + fq];
        acc[tl] = __builtin_amdgcn_mfma_f32_16x16x32_bf16(
            af, bones, (f32x4){0.f, 0.f, 0.f, 0.f}, 0, 0, 0);
    }

    float invdeg = 1.f / fmaxf((float)deg, 1.f);
    if ((lane & 15) == 0) {
        int rbase = (lane >> 4) * 4;
        #pragma unroll
        for (int tl = 0; tl < 8; tl++)
            #pragma unroll
            for (int r = 0; r < 4; r++) {
                int row = tl * 16 + rbase + r;
                float v = (row < KC) ? acc[tl][r] * invdeg : (row == KC ? 1.f : 0.f);
                Sw[row] = f2bf(v);
            }
    }
    __syncthreads();
    unsigned lo = Sw[2 * lane], hi = Sw[2 * lane + 1];
    ((unsigned*)(Aout + (size_t)node * 128))[lane] = lo | (hi << 16);
}

// ---------------- buildA (levels 2/3): inline slots + MFMA + LDS-bounce writeout ----
__global__ __launch_bounds__(256) void buildA_kernel(
    const float* __restrict__ posL, const int* __restrict__ src,
    const int* __restrict__ rowptr, const unsigned short* __restrict__ xbf,
    float rinv2, int sinkrow, int nodeBase, unsigned short* __restrict__ Aout)
{
    __shared__ __attribute__((aligned(16))) unsigned short BUF[8192];
    __shared__ int Es[EPB];
    unsigned short* S  = BUF;                // [128][SSTR]
    unsigned short* XT = BUF + 128 * SSTR;   // [64][XSTR]
    int node = nodeBase + blockIdx.x;
    int t = threadIdx.x;                      // blockDim = 256
    int rs = rowptr[node], re = rowptr[node + 1];
    int ne = re - rs;                         // <= 32 (max_nb)
    int wave = t >> 6, lane = t & 63;
    int fr = lane & 15, fq = (lane >> 4) * 8;
    int quad = lane >> 4;

    for (int i = t; i < 128 * SSTR / 8; i += 256)
        ((uint4*)S)[i] = make_uint4(0, 0, 0, 0);
    if (ne < EPB)
        for (int i = t; i < 64 * XSTR / 8; i += 256)
            ((uint4*)XT)[i] = make_uint4(0, 0, 0, 0);
    if (t < ne) Es[t] = src[rs + t];
    __syncthreads();

    if (t < ne)
        spline_scatter(posL, Es[t], node, rinv2, sinkrow, S, SSTR, t);
    for (int i = t; i < ne * 64; i += 256) {
        int c = i & 63, el = i >> 6;
        XT[c * XSTR + el] = xbf[(size_t)Es[el] * 64 + c];
    }
    __syncthreads();

    f32x4 acc[2][4];
    #pragma unroll
    for (int i = 0; i < 2; i++)
        #pragma unroll
        for (int j = 0; j < 4; j++) acc[i][j] = (f32x4){0.f, 0.f, 0.f, 0.f};
    #pragma unroll
    for (int i = 0; i < 2; i++) {
        bf16x8 af = *(const bf16x8*)&S[((2 * wave + i) * 16 + fr) * SSTR + fq];
        #pragma unroll
        for (int j = 0; j < 4; j++) {
            bf16x8 bg = *(const bf16x8*)&XT[(j * 16 + fr) * XSTR + fq];
            acc[i][j] = __builtin_amdgcn_mfma_f32_16x16x32_bf16(af, bg, acc[i][j], 0, 0, 0);
        }
    }
    __syncthreads();   // all LDS reads of S/XT complete; BUF is now free

    float invdeg = 1.f / fmaxf((float)ne, 1.f);
    #pragma unroll
    for (int i = 0; i < 2; i++) {
        int wibase = (2 * wave + i) * 16 + quad * 4;
        #pragma unroll
        for (int r = 0; r < 4; r++) {
            int wi = wibase + r;
            if (wi < KC) {
                #pragma unroll
                for (int j = 0; j < 4; j++)
                    BUF[wi * 64 + j * 16 + fr] = f2bf(acc[i][j][r] * invdeg);
            }
        }
    }
    if (t < 64) BUF[8000 + t] = xbf[(size_t)node * 64 + t];
    else if (t < 192) BUF[8000 + t] = 0;
    __syncthreads();

    uint4* out4 = (uint4*)(Aout + (size_t)blockIdx.x * KPAD);
    const uint4* b4 = (const uint4*)BUF;
    #pragma unroll
    for (int k = 0; k < 4; k++) out4[t + k * 256] = b4[t + k * 256];
}

// ---------------- bf16 MFMA GEMM, 64x64 tile, global_load_lds + counted vmcnt ------
// Epilogue modes: outBf!=0 -> write f2bf(elu(acc+bias)) (level 1, no K-split);
// else atomic-accumulate f32 into Pacc (levels 2/3 K-split reduction, P eliminated).
#define LDSOFF(row, colsh) (((row) << 6) + ((colsh) ^ (((row) & 7) << 3)))
__global__ __launch_bounds__(256) void gemm_kernel(const unsigned short* __restrict__ A,
                                                   const unsigned short* __restrict__ BT,
                                                   int Mrows, int COUT, int Ksz, int lda,
                                                   float* __restrict__ Pacc,
                                                   unsigned short* __restrict__ outBf,
                                                   const float* __restrict__ bias)
{
    __shared__ __attribute__((aligned(16))) unsigned short As[2 * 64 * 64];
    __shared__ __attribute__((aligned(16))) unsigned short Bs[2 * 64 * 64];
    int t = threadIdx.x;
    int mblk = blockIdx.x * 64, nblk = blockIdx.y * 64;
    int kBase = blockIdx.z * Ksz;

    int wave = t >> 6, lane = t & 63;
    int r0 = (wave << 3) + (lane >> 3);           // 0..31 (row for staging issues)
    int ccx = (lane & 7) ^ (r0 & 7);              // inverse-swizzled source chunk
    const unsigned short* ApB = A + (size_t)(mblk + r0) * lda + kBase + (ccx << 3);
    const unsigned short* BpB = BT + (size_t)(nblk + r0) * lda + kBase + (ccx << 3);
    size_t rstep32 = (size_t)32 * lda;

    int mw = (wave & 1) * 32, nw = (wave >> 1) * 32;
    int fr = lane & 15;
    int fq = (lane >> 4) * 8;

    f32x4 acc[2][2];
    #pragma unroll
    for (int i = 0; i < 2; i++)
        #pragma unroll
        for (int j = 0; j < 2; j++) acc[i][j] = (f32x4){0.f, 0.f, 0.f, 0.f};

    // prologue: stage tile 0 into buffer 0 (4 loads/wave, left in flight)
    gll16(ApB,           &As[(wave << 9)]);
    gll16(ApB + rstep32, &As[2048 + (wave << 9)]);
    gll16(BpB,           &Bs[(wave << 9)]);
    gll16(BpB + rstep32, &Bs[2048 + (wave << 9)]);

    int ktiles = Ksz / 64;
    for (int kt = 0; kt < ktiles; kt++) {
        int cur = (kt & 1) * 4096;
        if (kt + 1 < ktiles) {
            int nxt = ((kt + 1) & 1) * 4096;
            const unsigned short* Apn = ApB + (kt + 1) * 64;
            const unsigned short* Bpn = BpB + (kt + 1) * 64;
            gll16(Apn,           &As[nxt + (wave << 9)]);
            gll16(Apn + rstep32, &As[nxt + 2048 + (wave << 9)]);
            gll16(Bpn,           &Bs[nxt + (wave << 9)]);
            gll16(Bpn + rstep32, &Bs[nxt + 2048 + (wave << 9)]);
            asm volatile("s_waitcnt vmcnt(4)" ::: "memory");   // tile kt landed; kt+1 in flight
        } else {
            asm volatile("s_waitcnt vmcnt(0)" ::: "memory");   // last tile: drain
        }
        __builtin_amdgcn_s_barrier();   // all waves' tile-kt stages complete
        #pragma unroll
        for (int ks = 0; ks < 2; ks++) {
            bf16x8 af0 = *(const bf16x8*)&As[cur + LDSOFF(mw + fr,      ks * 32 + fq)];
            bf16x8 af1 = *(const bf16x8*)&As[cur + LDSOFF(mw + 16 + fr, ks * 32 + fq)];
            bf16x8 bg0 = *(const bf16x8*)&Bs[cur + LDSOFF(nw + fr,      ks * 32 + fq)];
            bf16x8 bg1 = *(const bf16x8*)&Bs[cur + LDSOFF(nw + 16 + fr, ks * 32 + fq)];
            acc[0][0] = __builtin_amdgcn_mfma_f32_16x16x32_bf16(af0, bg0, acc[0][0], 0, 0, 0);
            acc[0][1] = __builtin_amdgcn_mfma_f32_16x16x32_bf16(af0, bg1, acc[0][1], 0, 0, 0);
            acc[1][0] = __builtin_amdgcn_mfma_f32_16x16x32_bf16(af1, bg0, acc[1][0], 0, 0, 0);
            acc[1][1] = __builtin_amdgcn_mfma_f32_16x16x32_bf16(af1, bg1, acc[1][1], 0, 0, 0);
        }
        if (kt + 1 < ktiles)
            __builtin_amdgcn_s_barrier();  // reads of buf[kt&1] done before re-stage
    }
    int crow = (lane >> 4) * 4, ccol = lane & 15;
    if (outBf) {
        #pragma unroll
        for (int i = 0; i < 2; i++)
            #pragma unroll
            for (int j = 0; j < 2; j++) {
                int m0 = mblk + mw + i * 16 + crow;
                int n0 = nblk + nw + j * 16 + ccol;
                float bv = bias[n0];
                #pragma unroll
                for (int r = 0; r < 4; r++)
                    outBf[(size_t)(m0 + r) * COUT + n0] = f2bf(elu_f(acc[i][j][r] + bv));
            }
    } else {
        #pragma unroll
        for (int i = 0; i < 2; i++)
            #pragma unroll
            for (int j = 0; j < 2; j++) {
                int m0 = mblk + mw + i * 16 + crow;
                int n0 = nblk + nw + j * 16 + ccol;
                #pragma unroll
                for (int r = 0; r < 4; r++)
                    fadd_atomic(&Pacc[(size_t)(m0 + r) * COUT + n0], acc[i][j][r]);
            }
    }
}

// ---------------- bf16 gather (level-1 out -> level-2 in) ----------------
__global__ void xgather_kernel(const unsigned short* __restrict__ x_src,
                               const int* __restrict__ idx,
                               int n, unsigned short* __restrict__ x_dst)
{
    int tid = blockIdx.x * blockDim.x + threadIdx.x;
    if (tid >= n * 64) return;
    int i = tid >> 6, c = tid & 63;
    x_dst[tid] = x_src[(size_t)idx[i] * 64 + c];
}

// ---------------- level-2 acc -> bias+ELU+gather -> x3in bf16 ----------------
__global__ void cg23_kernel(const float* __restrict__ x2acc, const float* __restrict__ b,
                            const int* __restrict__ idx2, int n3,
                            unsigned short* __restrict__ x3in)
{
    int i = blockIdx.x * blockDim.x + threadIdx.x;
    if (i >= n3 * 64) return;
    int r = i >> 6, c = i & 63;
    x3in[i] = f2bf(elu_f(x2acc[(size_t)idx2[r] * 64 + c] + b[c]));
}

// ---------------- level-3 acc -> bias+ELU -> mean-pool accumulation ----------------
__global__ void combinepool_kernel(const float* __restrict__ x3acc, const float* __restrict__ b,
                                   const int* __restrict__ cid, int n3,
                                   float* __restrict__ gnum)
{
    int i = blockIdx.x * blockDim.x + threadIdx.x;
    if (i >= n3 * 128) return;
    int r = i >> 7, c = i & 127;
    float v = elu_f(x3acc[i] + b[c]);
    fadd_atomic(&gnum[cid[r] * 128 + c], v);
}

// ---------------- Final MLP + log_softmax ----------------
__global__ void mlp_kernel(const float* __restrict__ gnum, const float* __restrict__ cnt,
                           const float* __restrict__ lw1, const float* __restrict__ lb1,
                           const float* __restrict__ lw2, const float* __restrict__ lb2,
                           const float* __restrict__ lw3, const float* __restrict__ lb3,
                           float* __restrict__ out)
{
    __shared__ float gv[128], h1[256], h2[256], lg[10];
    __shared__ float lse_s;
    int cl = blockIdx.x, t = threadIdx.x;   // blockDim = 256
    if (t < 128) gv[t] = gnum[cl * 128 + t] / fmaxf(cnt[cl], 1.f);
    __syncthreads();
    float a = lb1[t];
    for (int c = 0; c < 128; c++) a += gv[c] * lw1[c * 256 + t];
    h1[t] = elu_f(a);
    __syncthreads();
    a = lb2[t];
    for (int c = 0; c < 256; c++) a += h1[c] * lw2[c * 256 + t];
    h2[t] = elu_f(a);
    __syncthreads();
    if (t < 10) {
        a = lb3[t];
        for (int c = 0; c < 256; c++) a += h2[c] * lw3[c * 10 + t];
        lg[t] = a;
    }
    __syncthreads();
    if (t == 0) {
        float m = -1e30f;
        for (int i = 0; i < 10; i++) m = fmaxf(m, lg[i]);
        float s = 0.f;
        for (int i = 0; i < 10; i++) s += expf(lg[i] - m);
        lse_s = m + logf(s);
    }
    __syncthreads();
    if (t < 10) out[cl * 10 + t] = lg[t] - lse_s;
}

extern "C" void kernel_launch(void* const* d_in, const int* in_sizes, int n_in,
                              void* d_out, int out_size, void* d_ws, size_t ws_size,
                              hipStream_t stream)
{
    const float* pos   = (const float*)d_in[0];
    const int*   batch = (const int*)d_in[1];
    const int*   src1  = (const int*)d_in[2];
    const int*   tgt1  = (const int*)d_in[3];
    const int*   src2  = (const int*)d_in[4];
    const int*   tgt2  = (const int*)d_in[5];
    const int*   src3  = (const int*)d_in[6];
    const int*   tgt3  = (const int*)d_in[7];
    const int*   idx1  = (const int*)d_in[8];
    const int*   idx2  = (const int*)d_in[9];
    const float* W1 = (const float*)d_in[10];
    const float* R1 = (const float*)d_in[11];
    const float* b1 = (const float*)d_in[12];
    const float* W2 = (const float*)d_in[13];
    const float* R2 = (const float*)d_in[14];
    const float* b2 = (const float*)d_in[15];
    const float* W3 = (const float*)d_in[16];
    const float* R3 = (const float*)d_in[17];
    const float* b3 = (const float*)d_in[18];
    const float* lw1 = (const float*)d_in[19];
    const float* lb1 = (const float*)d_in[20];
    const float* lw2 = (const float*)d_in[21];
    const float* lb2 = (const float*)d_in[22];
    const float* lw3 = (const float*)d_in[23];
    const float* lb3 = (const float*)d_in[24];

    int n1 = in_sizes[0] / 3;
    int E1 = in_sizes[2];
    int E2 = in_sizes[4];
    int E3 = in_sizes[6];
    int n2 = in_sizes[8];
    int n3 = in_sizes[9];

    float* ws = (float*)d_ws;
    float* pos2 = ws;                               // n2*3
    float* pos3 = pos2 + (size_t)n2 * 3;            // n3*3
    float* gnum = pos3 + (size_t)n3 * 3;            // 16*128 (cnt follows contiguously)
    float* cnt  = gnum + 16 * 128;                  // 16
    int*   cid  = (int*)(cnt + 16);                 // n3
    float* x2acc = (float*)(cid + ((n3 + 4) & ~3)); // n2*64 f32 (atomic K-split acc)
    float* x3acc = x2acc + (size_t)n2 * 64;         // n3*128 f32
    unsigned short* x1bf = (unsigned short*)(x3acc + (size_t)n3 * 128);  // n1*64 bf16
    unsigned short* x2in = x1bf + (size_t)n1 * 64;                       // n2*64 bf16
    unsigned short* x3in = x2in + (size_t)n2 * 64;                       // n3*64 bf16
    unsigned short* WfT1 = x3in + (size_t)n3 * 64;                       // 64*128 bf16
    unsigned short* WfT2 = WfT1 + (size_t)64 * 128;        // 64*KPAD
    unsigned short* WfT3 = WfT2 + (size_t)64 * KPAD;       // 128*KPAD
    int*   rp1  = (int*)(WfT3 + (size_t)128 * KPAD);
    int*   rp2  = rp1 + ((n1 + 4) & ~3);
    int*   rp3  = rp2 + ((n2 + 4) & ~3);
    unsigned short* A1buf = (unsigned short*)(rp3 + ((n3 + 4) & ~3));  // n1*128 bf16
    unsigned short* Abuf = A1buf + (size_t)n1 * 128;

    size_t usedBytes = (size_t)((char*)Abuf - (char*)ws);
    size_t availBytes = ws_size > usedBytes ? ws_size - usedBytes : 0;
    int maxRows = (int)(availBytes / ((size_t)KPAD * 2));
    maxRows &= ~63;
    if (maxRows < 64) maxRows = 64;
    if (maxRows > MAXCHUNK) maxRows = MAXCHUNK;   // keep buildA->gemm chunk L3-resident
    int rows2 = min(maxRows, n2);
    int rows3 = min(maxRows, n3);

    float* out = (float*)d_out;
    int Ksz = KPAD / NSPLIT;

    // --- fused preprocessing ---
    {
        // stream-ordered zeroes BEFORE any atomic accumulation (round-12 lesson)
        hipMemsetAsync(gnum, 0, (16 * 128 + 16) * sizeof(float), stream);
        hipMemsetAsync(x2acc, 0, (size_t)n2 * 64 * sizeof(float), stream);
        hipMemsetAsync(x3acc, 0, (size_t)n3 * 128 * sizeof(float), stream);
        int tot = n2 * 3 + n3 * 3
                + (E1 + 1) + (E2 + 1) + (E3 + 1) + n3;
        pre_kernel<<<(tot + 255) / 256, 256, 0, stream>>>(
            pos, idx1, idx2, n2, n3, pos2, pos3,
            tgt1, E1, n1, rp1, tgt2, E2, rp2, tgt3, E3, rp3,
            batch, cid, cnt);
        wtT_kernel<<<386, 256, 0, stream>>>(W1, R1, WfT1, W2, R2, WfT2, W3, R3, WfT3);
    }

    // --- level 1: MFMA histogram + GEMM(K=128, fused bias+ELU+bf16) + gather ---
    histo1_kernel<<<n1 / 4, 256, 0, stream>>>(pos, src1, rp1, 2.5f, 126, A1buf);
    {
        dim3 g1(n1 / 64, 1, 1);
        gemm_kernel<<<g1, 256, 0, stream>>>(A1buf, WfT1, n1, 64, 128, 128,
                                            nullptr, x1bf, b1);
        xgather_kernel<<<(n2 * 64 + 255) / 256, 256, 0, stream>>>(x1bf, idx1, n2, x2in);
    }

    // --- level 2 (gemm K-split reduces via atomics into x2acc) ---
    for (int cs = 0; cs < n2; cs += rows2) {
        int cr = min(rows2, n2 - cs);
        buildA_kernel<<<cr, 256, 0, stream>>>(pos2, src2, rp2, x2in, 1.25f, 125, cs, Abuf);
        dim3 grid(cr / 64, 1, NSPLIT);
        gemm_kernel<<<grid, 256, 0, stream>>>(Abuf, WfT2, cr, 64, Ksz, KPAD,
                                              x2acc + (size_t)cs * 64, nullptr, nullptr);
    }
    cg23_kernel<<<(n3 * 64 + 255) / 256, 256, 0, stream>>>(x2acc, b2, idx2, n3, x3in);

    // --- level 3 (gemm atomics into x3acc; pool applies bias+ELU) ---
    for (int cs = 0; cs < n3; cs += rows3) {
        int cr = min(rows3, n3 - cs);
        buildA_kernel<<<cr, 256, 0, stream>>>(pos3, src3, rp3, x3in, 0.5f, 125, cs, Abuf);
        dim3 grid(cr / 64, 2, NSPLIT);
        gemm_kernel<<<grid, 256, 0, stream>>>(Abuf, WfT3, cr, 128, Ksz, KPAD,
                                              x3acc + (size_t)cs * 128, nullptr, nullptr);
    }
    combinepool_kernel<<<(n3 * 128 + 255) / 256, 256, 0, stream>>>(x3acc, b3, cid, n3, gnum);

    // --- head ---
    mlp_kernel<<<16, 256, 0, stream>>>(gnum, cnt, lw1, lb1, lw2, lb2, lw3, lb3, out);
}

// Round 15
// 343.943 us; speedup vs baseline: 1.1603x; 1.1603x over previous
//
#include <hip/hip_runtime.h>
#include <hip/hip_bf16.h>
#include <math.h>

#define KDIM 5
#define KC 125
#define KPAD 8192   // 125*64 spline rows + 64 root rows + 128 zero pad (levels 2/3)
#define EPB 32      // max_nb = 32 -> deg <= 32 always
#define NSPLIT 8    // GEMM K-split for levels 2/3 (1024 blocks -> 4/CU TLP)
#define SSTR 40     // buildA S row stride in bf16
#define XSTR 40     // buildA XT row stride in bf16
#define H1STR 40    // histo1 S row stride in bf16
#define MAXCHUNK 8192  // cap Abuf chunk at 128 MB so buildA->gemm stays L3-resident

typedef short bf16x8 __attribute__((ext_vector_type(8)));
typedef float f32x4 __attribute__((ext_vector_type(4)));

__device__ __forceinline__ float elu_f(float x) { return x > 0.f ? x : (expf(x) - 1.f); }

__device__ __forceinline__ void fadd_atomic(float* p, float v) {
    unsafeAtomicAdd(p, v);
}

__device__ __forceinline__ unsigned short f2bf(float x) {
    union { float f; unsigned u; } v; v.f = x;
    unsigned r = (v.u + 0x7FFFu + ((v.u >> 16) & 1u)) >> 16;
    return (unsigned short)r;
}

// async 16B global->LDS (dest = wave-uniform base + lane*16)
__device__ __forceinline__ void gll16(const unsigned short* g, unsigned short* l) {
    __builtin_amdgcn_global_load_lds(
        (const __attribute__((address_space(1))) unsigned int*)g,
        (__attribute__((address_space(3))) unsigned int*)l, 16, 0, 0);
}

// inline spline-weight scatter (w==0 duplicates -> sinkrow)
__device__ __forceinline__ void spline_scatter(
    const float* __restrict__ posL, int s, int node, float rinv2, int sinkrow,
    unsigned short* __restrict__ S, int stride, int ecol)
{
    float p0 = fminf(fmaxf((posL[node*3+0] - posL[s*3+0]) * rinv2 + 0.5f, 0.f), 1.f);
    float p1 = fminf(fmaxf((posL[node*3+1] - posL[s*3+1]) * rinv2 + 0.5f, 0.f), 1.f);
    float p2 = fminf(fmaxf((posL[node*3+2] - posL[s*3+2]) * rinv2 + 0.5f, 0.f), 1.f);
    float v0 = p0 * (KDIM - 1), v1 = p1 * (KDIM - 1), v2 = p2 * (KDIM - 1);
    int b0 = (int)floorf(v0), b1 = (int)floorf(v1), b2 = (int)floorf(v2);
    float f0 = v0 - (float)b0, f1 = v1 - (float)b1, f2 = v2 - (float)b2;
    #pragma unroll
    for (int sb = 0; sb < 8; sb++) {
        int i0 = sb & 1, i1 = (sb >> 1) & 1, i2 = (sb >> 2) & 1;
        float w = (i0 ? f0 : 1.f - f0) * (i1 ? f1 : 1.f - f1) * (i2 ? f2 : 1.f - f2);
        int k0 = min(b0 + i0, KDIM - 1), k1 = min(b1 + i1, KDIM - 1), k2 = min(b2 + i2, KDIM - 1);
        int wi = k0 + KDIM * k1 + KDIM * KDIM * k2;
        if (w == 0.f) wi = sinkrow;
        S[wi * stride + ecol] = f2bf(w);
    }
}

// ---------------- rowptr segment ----------------
__device__ __forceinline__ void rowptr_seg(const int* __restrict__ tgt, int E, int n,
                                           int* __restrict__ rowptr, int e)
{
    if (e < E) {
        int t = tgt[e];
        int p = (e == 0) ? -1 : tgt[e - 1];
        for (int v = p + 1; v <= t; v++) rowptr[v] = e;
    } else {   // e == E
        int p = tgt[E - 1];
        for (int v = p + 1; v <= n; v++) rowptr[v] = E;
    }
}

// pre: pos gathers + rowptr x3 + cid/cnt -- single launch.
// gnum/cnt zeroed by stream-ordered hipMemsetAsync BEFORE this launch (round-12 lesson).
__global__ void pre_kernel(
    const float* __restrict__ pos, const int* __restrict__ idx1, const int* __restrict__ idx2,
    int n2, int n3,
    float* __restrict__ pos2, float* __restrict__ pos3,
    const int* __restrict__ tgt1, int E1, int n1, int* __restrict__ rp1,
    const int* __restrict__ tgt2, int E2, int* __restrict__ rp2,
    const int* __restrict__ tgt3, int E3, int* __restrict__ rp3,
    const int* __restrict__ batch, int* __restrict__ cid, float* __restrict__ cnt)
{
    int i = blockIdx.x * blockDim.x + threadIdx.x;
    int w0 = n2 * 3, w1 = w0 + n3 * 3;
    int e0 = w1 + E1 + 1, e1 = e0 + E2 + 1, e2 = e1 + E3 + 1, e3 = e2 + n3;
    if (i < w0) {
        int r = i / 3, d = i - r * 3;
        pos2[i] = pos[idx1[r] * 3 + d];
    } else if (i < w1) {
        int j = i - w0;
        int r = j / 3, d = j - r * 3;
        pos3[j] = pos[idx1[idx2[r]] * 3 + d];
    } else if (i < e0) {
        rowptr_seg(tgt1, E1, n1, rp1, i - w1);
    } else if (i < e1) {
        rowptr_seg(tgt2, E2, n2, rp2, i - e0);
    } else if (i < e2) {
        rowptr_seg(tgt3, E3, n3, rp3, i - e1);
    } else if (i < e3) {
        int j = i - e2;
        int cl = batch[idx1[idx2[j]]];
        cid[j] = cl;
        int lane = threadIdx.x & 63;
        #pragma unroll
        for (int c = 0; c < 16; c++) {
            unsigned long long m = __ballot(cl == c);
            if (m != 0ULL && lane == __ffsll((long long)m) - 1)
                fadd_atomic(&cnt[c], (float)__popcll(m));
        }
    }
}

// ---------------- tiled transpose, all three weight sets in ONE launch ------------
__global__ __launch_bounds__(256) void wtT_kernel(
    const float* __restrict__ W1, const float* __restrict__ R1, unsigned short* __restrict__ WfT1,
    const float* __restrict__ W2, const float* __restrict__ R2, unsigned short* __restrict__ WfT2,
    const float* __restrict__ W3, const float* __restrict__ R3, unsigned short* __restrict__ WfT3)
{
    __shared__ unsigned short L[64 * 65];
    int bt = blockIdx.x;
    const float *W, *R;
    unsigned short* WfT;
    int COUT, kpad, krows, cin, ntk;
    if (bt < 2)        { W = W1; R = R1; WfT = WfT1; COUT = 64;  kpad = 128;  krows = KC;      cin = 1;  ntk = 2;   }
    else if (bt < 130) { W = W2; R = R2; WfT = WfT2; COUT = 64;  kpad = KPAD; krows = KC * 64; cin = 64; ntk = 128; bt -= 2;   }
    else               { W = W3; R = R3; WfT = WfT3; COUT = 128; kpad = KPAD; krows = KC * 64; cin = 64; ntk = 128; bt -= 130; }
    int kt = (bt % ntk) * 64;
    int nt = (bt / ntk) * 64;
    int t = threadIdx.x;
    int ncol = t & 63, rowgrp = t >> 6;
    #pragma unroll
    for (int j = 0; j < 16; j++) {
        int row = j * 4 + rowgrp;     // 0..63
        int k = kt + row;
        int n = nt + ncol;
        float v = 0.f;
        if (k < krows) v = W[(size_t)k * COUT + n];
        else if (k < krows + cin) v = R[(size_t)(k - krows) * COUT + n];
        L[row * 65 + ncol] = f2bf(v);
    }
    __syncthreads();
    int n = nt + (t >> 2);
    int k0 = (t & 3) * 16;
    __attribute__((aligned(16))) unsigned short tmp[16];
    #pragma unroll
    for (int j = 0; j < 16; j++) tmp[j] = L[(k0 + j) * 65 + (t >> 2)];
    *(uint4*)&WfT[(size_t)n * kpad + kt + k0]     = *(uint4*)&tmp[0];
    *(uint4*)&WfT[(size_t)n * kpad + kt + k0 + 8] = *(uint4*)&tmp[8];
}

// ---------------- Level 1 histogram via MFMA row-sum, inline slot computation ------
__global__ __launch_bounds__(256) void histo1_kernel(const float* __restrict__ pos,
                                                     const int* __restrict__ src,
                                                     const int* __restrict__ rowptr,
                                                     float rinv2, int sinkrow,
                                                     unsigned short* __restrict__ Aout)
{
    __shared__ __attribute__((aligned(16))) unsigned short S[4][128 * H1STR];
    int wave = threadIdx.x >> 6, lane = threadIdx.x & 63;
    int node = blockIdx.x * 4 + wave;
    int rs = rowptr[node], re = rowptr[node + 1];
    int deg = re - rs;
    unsigned short* Sw = S[wave];

    for (int i = lane; i < 128 * H1STR / 8; i += 64)
        ((uint4*)Sw)[i] = make_uint4(0, 0, 0, 0);
    __syncthreads();

    if (lane < deg)
        spline_scatter(pos, src[rs + lane], node, rinv2, sinkrow, Sw, H1STR, lane);
    __syncthreads();

    const short one = 0x3F80;
    bf16x8 bones = {one, one, one, one, one, one, one, one};
    int fr = lane & 15, fq = (lane >> 4) * 8;
    f32x4 acc[8];
    #pragma unroll
    for (int tl = 0; tl < 8; tl++) {
        bf16x8 af = *(const bf16x8*)&Sw[(tl * 16 + fr) * H1STR + fq];
        acc[tl] = __builtin_amdgcn_mfma_f32_16x16x32_bf16(
            af, bones, (f32x4){0.f, 0.f, 0.f, 0.f}, 0, 0, 0);
    }

    float invdeg = 1.f / fmaxf((float)deg, 1.f);
    if ((lane & 15) == 0) {
        int rbase = (lane >> 4) * 4;
        #pragma unroll
        for (int tl = 0; tl < 8; tl++)
            #pragma unroll
            for (int r = 0; r < 4; r++) {
                int row = tl * 16 + rbase + r;
                float v = (row < KC) ? acc[tl][r] * invdeg : (row == KC ? 1.f : 0.f);
                Sw[row] = f2bf(v);
            }
    }
    __syncthreads();
    unsigned lo = Sw[2 * lane], hi = Sw[2 * lane + 1];
    ((unsigned*)(Aout + (size_t)node * 128))[lane] = lo | (hi << 16);
}

// ---------------- buildA (levels 2/3): inline slots + MFMA + LDS-bounce writeout ----
__global__ __launch_bounds__(256) void buildA_kernel(
    const float* __restrict__ posL, const int* __restrict__ src,
    const int* __restrict__ rowptr, const unsigned short* __restrict__ xbf,
    float rinv2, int sinkrow, int nodeBase, unsigned short* __restrict__ Aout)
{
    __shared__ __attribute__((aligned(16))) unsigned short BUF[8192];
    __shared__ int Es[EPB];
    unsigned short* S  = BUF;                // [128][SSTR]
    unsigned short* XT = BUF + 128 * SSTR;   // [64][XSTR]
    int node = nodeBase + blockIdx.x;
    int t = threadIdx.x;                      // blockDim = 256
    int rs = rowptr[node], re = rowptr[node + 1];
    int ne = re - rs;                         // <= 32 (max_nb)
    int wave = t >> 6, lane = t & 63;
    int fr = lane & 15, fq = (lane >> 4) * 8;
    int quad = lane >> 4;

    for (int i = t; i < 128 * SSTR / 8; i += 256)
        ((uint4*)S)[i] = make_uint4(0, 0, 0, 0);
    if (ne < EPB)
        for (int i = t; i < 64 * XSTR / 8; i += 256)
            ((uint4*)XT)[i] = make_uint4(0, 0, 0, 0);
    if (t < ne) Es[t] = src[rs + t];
    __syncthreads();

    if (t < ne)
        spline_scatter(posL, Es[t], node, rinv2, sinkrow, S, SSTR, t);
    for (int i = t; i < ne * 64; i += 256) {
        int c = i & 63, el = i >> 6;
        XT[c * XSTR + el] = xbf[(size_t)Es[el] * 64 + c];
    }
    __syncthreads();

    f32x4 acc[2][4];
    #pragma unroll
    for (int i = 0; i < 2; i++)
        #pragma unroll
        for (int j = 0; j < 4; j++) acc[i][j] = (f32x4){0.f, 0.f, 0.f, 0.f};
    #pragma unroll
    for (int i = 0; i < 2; i++) {
        bf16x8 af = *(const bf16x8*)&S[((2 * wave + i) * 16 + fr) * SSTR + fq];
        #pragma unroll
        for (int j = 0; j < 4; j++) {
            bf16x8 bg = *(const bf16x8*)&XT[(j * 16 + fr) * XSTR + fq];
            acc[i][j] = __builtin_amdgcn_mfma_f32_16x16x32_bf16(af, bg, acc[i][j], 0, 0, 0);
        }
    }
    __syncthreads();   // all LDS reads of S/XT complete; BUF is now free

    float invdeg = 1.f / fmaxf((float)ne, 1.f);
    #pragma unroll
    for (int i = 0; i < 2; i++) {
        int wibase = (2 * wave + i) * 16 + quad * 4;
        #pragma unroll
        for (int r = 0; r < 4; r++) {
            int wi = wibase + r;
            if (wi < KC) {
                #pragma unroll
                for (int j = 0; j < 4; j++)
                    BUF[wi * 64 + j * 16 + fr] = f2bf(acc[i][j][r] * invdeg);
            }
        }
    }
    if (t < 64) BUF[8000 + t] = xbf[(size_t)node * 64 + t];
    else if (t < 192) BUF[8000 + t] = 0;
    __syncthreads();

    uint4* out4 = (uint4*)(Aout + (size_t)blockIdx.x * KPAD);
    const uint4* b4 = (const uint4*)BUF;
    #pragma unroll
    for (int k = 0; k < 4; k++) out4[t + k * 256] = b4[t + k * 256];
}

// ---------------- bf16 MFMA GEMM, 64x64 tile, global_load_lds + counted vmcnt ------
// Epilogue: outBf!=0 -> fused bias+ELU+bf16 store (level 1, single K-split);
// else plain f32 store into private P plane (levels 2/3; combine reduces).
#define LDSOFF(row, colsh) (((row) << 6) + ((colsh) ^ (((row) & 7) << 3)))
__global__ __launch_bounds__(256) void gemm_kernel(const unsigned short* __restrict__ A,
                                                   const unsigned short* __restrict__ BT,
                                                   int Mrows, int COUT, int Ksz, int lda,
                                                   float* __restrict__ P,
                                                   unsigned short* __restrict__ outBf,
                                                   const float* __restrict__ bias)
{
    __shared__ __attribute__((aligned(16))) unsigned short As[2 * 64 * 64];
    __shared__ __attribute__((aligned(16))) unsigned short Bs[2 * 64 * 64];
    int t = threadIdx.x;
    int mblk = blockIdx.x * 64, nblk = blockIdx.y * 64;
    int kBase = blockIdx.z * Ksz;

    int wave = t >> 6, lane = t & 63;
    int r0 = (wave << 3) + (lane >> 3);           // 0..31 (row for staging issues)
    int ccx = (lane & 7) ^ (r0 & 7);              // inverse-swizzled source chunk
    const unsigned short* ApB = A + (size_t)(mblk + r0) * lda + kBase + (ccx << 3);
    const unsigned short* BpB = BT + (size_t)(nblk + r0) * lda + kBase + (ccx << 3);
    size_t rstep32 = (size_t)32 * lda;

    int mw = (wave & 1) * 32, nw = (wave >> 1) * 32;
    int fr = lane & 15;
    int fq = (lane >> 4) * 8;

    f32x4 acc[2][2];
    #pragma unroll
    for (int i = 0; i < 2; i++)
        #pragma unroll
        for (int j = 0; j < 2; j++) acc[i][j] = (f32x4){0.f, 0.f, 0.f, 0.f};

    // prologue: stage tile 0 into buffer 0 (4 loads/wave, left in flight)
    gll16(ApB,           &As[(wave << 9)]);
    gll16(ApB + rstep32, &As[2048 + (wave << 9)]);
    gll16(BpB,           &Bs[(wave << 9)]);
    gll16(BpB + rstep32, &Bs[2048 + (wave << 9)]);

    int ktiles = Ksz / 64;
    for (int kt = 0; kt < ktiles; kt++) {
        int cur = (kt & 1) * 4096;
        if (kt + 1 < ktiles) {
            int nxt = ((kt + 1) & 1) * 4096;
            const unsigned short* Apn = ApB + (kt + 1) * 64;
            const unsigned short* Bpn = BpB + (kt + 1) * 64;
            gll16(Apn,           &As[nxt + (wave << 9)]);
            gll16(Apn + rstep32, &As[nxt + 2048 + (wave << 9)]);
            gll16(Bpn,           &Bs[nxt + (wave << 9)]);
            gll16(Bpn + rstep32, &Bs[nxt + 2048 + (wave << 9)]);
            asm volatile("s_waitcnt vmcnt(4)" ::: "memory");   // tile kt landed; kt+1 in flight
        } else {
            asm volatile("s_waitcnt vmcnt(0)" ::: "memory");   // last tile: drain
        }
        __builtin_amdgcn_s_barrier();   // all waves' tile-kt stages complete
        #pragma unroll
        for (int ks = 0; ks < 2; ks++) {
            bf16x8 af0 = *(const bf16x8*)&As[cur + LDSOFF(mw + fr,      ks * 32 + fq)];
            bf16x8 af1 = *(const bf16x8*)&As[cur + LDSOFF(mw + 16 + fr, ks * 32 + fq)];
            bf16x8 bg0 = *(const bf16x8*)&Bs[cur + LDSOFF(nw + fr,      ks * 32 + fq)];
            bf16x8 bg1 = *(const bf16x8*)&Bs[cur + LDSOFF(nw + 16 + fr, ks * 32 + fq)];
            acc[0][0] = __builtin_amdgcn_mfma_f32_16x16x32_bf16(af0, bg0, acc[0][0], 0, 0, 0);
            acc[0][1] = __builtin_amdgcn_mfma_f32_16x16x32_bf16(af0, bg1, acc[0][1], 0, 0, 0);
            acc[1][0] = __builtin_amdgcn_mfma_f32_16x16x32_bf16(af1, bg0, acc[1][0], 0, 0, 0);
            acc[1][1] = __builtin_amdgcn_mfma_f32_16x16x32_bf16(af1, bg1, acc[1][1], 0, 0, 0);
        }
        if (kt + 1 < ktiles)
            __builtin_amdgcn_s_barrier();  // reads of buf[kt&1] done before re-stage
    }
    int crow = (lane >> 4) * 4, ccol = lane & 15;
    if (outBf) {
        #pragma unroll
        for (int i = 0; i < 2; i++)
            #pragma unroll
            for (int j = 0; j < 2; j++) {
                int m0 = mblk + mw + i * 16 + crow;
                int n0 = nblk + nw + j * 16 + ccol;
                float bv = bias[n0];
                #pragma unroll
                for (int r = 0; r < 4; r++)
                    outBf[(size_t)(m0 + r) * COUT + n0] = f2bf(elu_f(acc[i][j][r] + bv));
            }
    } else {
        float* Pz = P + (size_t)blockIdx.z * Mrows * COUT;
        #pragma unroll
        for (int i = 0; i < 2; i++)
            #pragma unroll
            for (int j = 0; j < 2; j++) {
                int m0 = mblk + mw + i * 16 + crow;
                int n0 = nblk + nw + j * 16 + ccol;
                #pragma unroll
                for (int r = 0; r < 4; r++)
                    Pz[(size_t)(m0 + r) * COUT + n0] = acc[i][j][r];
            }
    }
}

// ---------------- combine K-split partials + bias + ELU -> bf16 (level 2) ----------
__global__ void combine2_kernel(const float* __restrict__ P, const float* __restrict__ b,
                                int Mrows, int NS, unsigned short* __restrict__ xout)
{
    int i = blockIdx.x * blockDim.x + threadIdx.x;
    int total = Mrows * 64;
    if (i >= total) return;
    float s = 0.f;
    for (int z = 0; z < NS; z++) s += P[(size_t)z * total + i];
    xout[i] = f2bf(elu_f(s + b[i & 63]));
}

// ---------------- level-3 combine fused with mean-pool accumulation ----------------
__global__ void combinepool_kernel(const float* __restrict__ P, const float* __restrict__ b,
                                   const int* __restrict__ cid, int cs, int Mrows, int NS,
                                   float* __restrict__ gnum)
{
    int i = blockIdx.x * blockDim.x + threadIdx.x;
    int total = Mrows * 128;
    if (i >= total) return;
    int r = i >> 7, c = i & 127;
    float s = 0.f;
    for (int z = 0; z < NS; z++) s += P[(size_t)z * total + i];
    float v = elu_f(s + b[c]);
    fadd_atomic(&gnum[cid[cs + r] * 128 + c], v);
}

// ---------------- gather bf16 -> bf16 ----------------
__global__ void xgather_kernel(const unsigned short* __restrict__ x_src,
                               const int* __restrict__ idx,
                               int n, unsigned short* __restrict__ x_dst)
{
    int tid = blockIdx.x * blockDim.x + threadIdx.x;
    if (tid >= n * 64) return;
    int i = tid >> 6, c = tid & 63;
    x_dst[tid] = x_src[(size_t)idx[i] * 64 + c];
}

// ---------------- Final MLP + log_softmax ----------------
__global__ void mlp_kernel(const float* __restrict__ gnum, const float* __restrict__ cnt,
                           const float* __restrict__ lw1, const float* __restrict__ lb1,
                           const float* __restrict__ lw2, const float* __restrict__ lb2,
                           const float* __restrict__ lw3, const float* __restrict__ lb3,
                           float* __restrict__ out)
{
    __shared__ float gv[128], h1[256], h2[256], lg[10];
    __shared__ float lse_s;
    int cl = blockIdx.x, t = threadIdx.x;   // blockDim = 256
    if (t < 128) gv[t] = gnum[cl * 128 + t] / fmaxf(cnt[cl], 1.f);
    __syncthreads();
    float a = lb1[t];
    for (int c = 0; c < 128; c++) a += gv[c] * lw1[c * 256 + t];
    h1[t] = elu_f(a);
    __syncthreads();
    a = lb2[t];
    for (int c = 0; c < 256; c++) a += h1[c] * lw2[c * 256 + t];
    h2[t] = elu_f(a);
    __syncthreads();
    if (t < 10) {
        a = lb3[t];
        for (int c = 0; c < 256; c++) a += h2[c] * lw3[c * 10 + t];
        lg[t] = a;
    }
    __syncthreads();
    if (t == 0) {
        float m = -1e30f;
        for (int i = 0; i < 10; i++) m = fmaxf(m, lg[i]);
        float s = 0.f;
        for (int i = 0; i < 10; i++) s += expf(lg[i] - m);
        lse_s = m + logf(s);
    }
    __syncthreads();
    if (t < 10) out[cl * 10 + t] = lg[t] - lse_s;
}

extern "C" void kernel_launch(void* const* d_in, const int* in_sizes, int n_in,
                              void* d_out, int out_size, void* d_ws, size_t ws_size,
                              hipStream_t stream)
{
    const float* pos   = (const float*)d_in[0];
    const int*   batch = (const int*)d_in[1];
    const int*   src1  = (const int*)d_in[2];
    const int*   tgt1  = (const int*)d_in[3];
    const int*   src2  = (const int*)d_in[4];
    const int*   tgt2  = (const int*)d_in[5];
    const int*   src3  = (const int*)d_in[6];
    const int*   tgt3  = (const int*)d_in[7];
    const int*   idx1  = (const int*)d_in[8];
    const int*   idx2  = (const int*)d_in[9];
    const float* W1 = (const float*)d_in[10];
    const float* R1 = (const float*)d_in[11];
    const float* b1 = (const float*)d_in[12];
    const float* W2 = (const float*)d_in[13];
    const float* R2 = (const float*)d_in[14];
    const float* b2 = (const float*)d_in[15];
    const float* W3 = (const float*)d_in[16];
    const float* R3 = (const float*)d_in[17];
    const float* b3 = (const float*)d_in[18];
    const float* lw1 = (const float*)d_in[19];
    const float* lb1 = (const float*)d_in[20];
    const float* lw2 = (const float*)d_in[21];
    const float* lb2 = (const float*)d_in[22];
    const float* lw3 = (const float*)d_in[23];
    const float* lb3 = (const float*)d_in[24];

    int n1 = in_sizes[0] / 3;
    int E1 = in_sizes[2];
    int E2 = in_sizes[4];
    int E3 = in_sizes[6];
    int n2 = in_sizes[8];
    int n3 = in_sizes[9];

    float* ws = (float*)d_ws;
    float* pos2 = ws;                               // n2*3
    float* pos3 = pos2 + (size_t)n2 * 3;            // n3*3
    float* gnum = pos3 + (size_t)n3 * 3;            // 16*128 (cnt follows contiguously)
    float* cnt  = gnum + 16 * 128;                  // 16
    int*   cid  = (int*)(cnt + 16);                 // n3
    unsigned short* x1bf = (unsigned short*)(cid + ((n3 + 4) & ~3));   // n1*64 bf16
    unsigned short* x2o  = x1bf + (size_t)n1 * 64;                     // n2*64 bf16
    unsigned short* x2in = x2o  + (size_t)n2 * 64;                     // n2*64 bf16
    unsigned short* x3in = x2in + (size_t)n2 * 64;                     // n3*64 bf16
    unsigned short* WfT1 = x3in + (size_t)n3 * 64;                     // 64*128 bf16
    unsigned short* WfT2 = WfT1 + (size_t)64 * 128;        // 64*KPAD
    unsigned short* WfT3 = WfT2 + (size_t)64 * KPAD;       // 128*KPAD
    int*   rp1  = (int*)(WfT3 + (size_t)128 * KPAD);
    int*   rp2  = rp1 + ((n1 + 4) & ~3);
    int*   rp3  = rp2 + ((n2 + 4) & ~3);
    unsigned short* A1buf = (unsigned short*)(rp3 + ((n3 + 4) & ~3));  // n1*128 bf16
    float*  P    = (float*)(A1buf + (size_t)n1 * 128);  // 8M floats
    unsigned short* Abuf = (unsigned short*)(P + (size_t)8 * 1024 * 1024);

    size_t usedBytes = (size_t)((char*)Abuf - (char*)ws);
    size_t availBytes = ws_size > usedBytes ? ws_size - usedBytes : 0;
    int maxRows = (int)(availBytes / ((size_t)KPAD * 2));
    maxRows &= ~63;
    if (maxRows < 64) maxRows = 64;
    if (maxRows > MAXCHUNK) maxRows = MAXCHUNK;   // keep buildA->gemm chunk L3-resident
    int rowsP2 = ((8 * 1024 * 1024) / (NSPLIT * 64)) & ~63;
    int rowsP3 = ((8 * 1024 * 1024) / (NSPLIT * 128)) & ~63;
    int rows2 = min(min(maxRows, rowsP2), n2);
    int rows3 = min(min(maxRows, rowsP3), n3);

    float* out = (float*)d_out;
    int Ksz = KPAD / NSPLIT;

    // --- fused preprocessing ---
    {
        // stream-ordered zero of gnum(2048)+cnt(16) BEFORE pre_kernel's cnt atomics
        hipMemsetAsync(gnum, 0, (16 * 128 + 16) * sizeof(float), stream);
        int tot = n2 * 3 + n3 * 3
                + (E1 + 1) + (E2 + 1) + (E3 + 1) + n3;
        pre_kernel<<<(tot + 255) / 256, 256, 0, stream>>>(
            pos, idx1, idx2, n2, n3, pos2, pos3,
            tgt1, E1, n1, rp1, tgt2, E2, rp2, tgt3, E3, rp3,
            batch, cid, cnt);
        wtT_kernel<<<386, 256, 0, stream>>>(W1, R1, WfT1, W2, R2, WfT2, W3, R3, WfT3);
    }

    // --- level 1: MFMA histogram + GEMM(K=128, fused bias+ELU+bf16) + gather ---
    histo1_kernel<<<n1 / 4, 256, 0, stream>>>(pos, src1, rp1, 2.5f, 126, A1buf);
    {
        dim3 g1(n1 / 64, 1, 1);
        gemm_kernel<<<g1, 256, 0, stream>>>(A1buf, WfT1, n1, 64, 128, 128,
                                            nullptr, x1bf, b1);
        xgather_kernel<<<(n2 * 64 + 255) / 256, 256, 0, stream>>>(x1bf, idx1, n2, x2in);
    }

    // --- level 2 (P planes + combine, round-13 structure) ---
    for (int cs = 0; cs < n2; cs += rows2) {
        int cr = min(rows2, n2 - cs);
        buildA_kernel<<<cr, 256, 0, stream>>>(pos2, src2, rp2, x2in, 1.25f, 125, cs, Abuf);
        dim3 grid(cr / 64, 1, NSPLIT);
        gemm_kernel<<<grid, 256, 0, stream>>>(Abuf, WfT2, cr, 64, Ksz, KPAD,
                                              P, nullptr, nullptr);
        combine2_kernel<<<(cr * 64 + 255) / 256, 256, 0, stream>>>(P, b2, cr, NSPLIT,
                                                                   x2o + (size_t)cs * 64);
    }
    xgather_kernel<<<(n3 * 64 + 255) / 256, 256, 0, stream>>>(x2o, idx2, n3, x3in);

    // --- level 3 (P planes + combinepool, round-13 structure) ---
    for (int cs = 0; cs < n3; cs += rows3) {
        int cr = min(rows3, n3 - cs);
        buildA_kernel<<<cr, 256, 0, stream>>>(pos3, src3, rp3, x3in, 0.5f, 125, cs, Abuf);
        dim3 grid(cr / 64, 2, NSPLIT);
        gemm_kernel<<<grid, 256, 0, stream>>>(Abuf, WfT3, cr, 128, Ksz, KPAD,
                                              P, nullptr, nullptr);
        combinepool_kernel<<<(cr * 128 + 255) / 256, 256, 0, stream>>>(P, b3, cid, cs, cr,
                                                                       NSPLIT, gnum);
    }

    // --- head ---
    mlp_kernel<<<16, 256, 0, stream>>>(gnum, cnt, lw1, lb1, lw2, lb2, lw3, lb3, out);
}